// Round 2
// baseline (973.089 us; speedup 1.0000x reference)
//
#include <hip/hip_runtime.h>
#include <math.h>

#define T_TOKENS    16384
#define D_MODEL     2048
#define NUM_EXPERTS 256
#define TOP_K       8

// d_out layout (floats): idx[16384*8] | weights[16384*8] | affinities[16384*256] | loss[1]
#define OUT_IDX  0
#define OUT_W    (T_TOKENS * TOP_K)
#define OUT_AFF  (2 * T_TOKENS * TOP_K)
#define OUT_LOSS (2 * T_TOKENS * TOP_K + T_TOKENS * NUM_EXPERTS)

// ws layout (bytes):
//   M      double[256*2048]      @ 0          (4 MiB)
//   res    float[16384*256]      @ 4 MiB      (16 MiB)  f32 residual of f64 affinity
//   sumP   double[256]           @ 20 MiB
//   counts float[256]            after sumP
#define WS_M_B    0
#define WS_RES_B  (NUM_EXPERTS * D_MODEL * 8)
#define WS_SUMP_B (WS_RES_B + (size_t)T_TOKENS * NUM_EXPERTS * 4)
#define WS_CNT_B  (WS_SUMP_B + NUM_EXPERTS * 8)

// ---------------------------------------------------------------------------
// Kernel A: M[e,k] = sum_d C[e,d]*W[d,k], f64 accumulate, f64 output.
// tile 32e x 64k, BK=32. grid (32, 8), 256 threads.
// ---------------------------------------------------------------------------
__global__ __launch_bounds__(256) void cw_gemm_f64(
    const float* __restrict__ C, const float* __restrict__ W,
    double* __restrict__ M)
{
    __shared__ double Cs[32][33];  // [d][e]
    __shared__ double Ws[32][68];  // [d][k]

    const int tid = threadIdx.x;
    const int tx = tid & 15;   // k: 4 cols strided by 16 -> conflict-free b64
    const int ty = tid >> 4;   // e: 2 rows
    const int e0 = blockIdx.y * 32;
    const int k0 = blockIdx.x * 64;

    double acc[2][4] = {{0,0,0,0},{0,0,0,0}};

    for (int d0 = 0; d0 < D_MODEL; d0 += 32) {
        {
            const int e = tid >> 3, d4 = (tid & 7) * 4;
            const float4 v = *(const float4*)(C + (size_t)(e0 + e) * D_MODEL + d0 + d4);
            Cs[d4 + 0][e] = v.x; Cs[d4 + 1][e] = v.y;
            Cs[d4 + 2][e] = v.z; Cs[d4 + 3][e] = v.w;
        }
        #pragma unroll
        for (int r = 0; r < 2; ++r) {
            const int idx = tid + r * 256;
            const int d = idx >> 4, k4 = (idx & 15) * 4;
            const float4 v = *(const float4*)(W + (size_t)(d0 + d) * D_MODEL + k0 + k4);
            Ws[d][k4 + 0] = v.x; Ws[d][k4 + 1] = v.y;
            Ws[d][k4 + 2] = v.z; Ws[d][k4 + 3] = v.w;
        }
        __syncthreads();
        #pragma unroll
        for (int dd = 0; dd < 32; ++dd) {
            const double a0 = Cs[dd][ty * 2 + 0];
            const double a1 = Cs[dd][ty * 2 + 1];
            double b[4];
            #pragma unroll
            for (int j = 0; j < 4; ++j) b[j] = Ws[dd][tx + 16 * j];
            #pragma unroll
            for (int j = 0; j < 4; ++j) { acc[0][j] += a0 * b[j]; acc[1][j] += a1 * b[j]; }
        }
        __syncthreads();
    }
    #pragma unroll
    for (int i = 0; i < 2; ++i) {
        const int e = e0 + ty * 2 + i;
        #pragma unroll
        for (int j = 0; j < 4; ++j)
            M[(size_t)e * D_MODEL + k0 + tx + 16 * j] = acc[i][j];
    }
}

// ---------------------------------------------------------------------------
// Kernel B: aff64[t,e] = sum_k H[t,k]*M[e,k] (f64). Writes f32 aff + f32
// residual (double-float), accumulates sumP[e] = sum_t sigmoid(aff64) in f64.
// tile 128t x 64e, BK=16. grid (4, 128), 256 threads, micro 8t x 4e.
// token micro-stride 16 -> conflict-free ds_read_b64.
// ---------------------------------------------------------------------------
__global__ __launch_bounds__(256) void affinity_f64(
    const float* __restrict__ H, const double* __restrict__ M,
    float* __restrict__ aff, float* __restrict__ res,
    double* __restrict__ sumP)
{
    __shared__ double Hs[16][129];  // [k][t]
    __shared__ double Ms[16][67];   // [k][e]

    const int tid = threadIdx.x;
    const int tt = tid & 15;   // token group: tokens tt + 16*i
    const int te = tid >> 4;   // expert group: experts te*4..te*4+3
    const int t0 = blockIdx.y * 128;
    const int e0 = blockIdx.x * 64;

    double acc[8][4];
    #pragma unroll
    for (int i = 0; i < 8; ++i)
        #pragma unroll
        for (int j = 0; j < 4; ++j) acc[i][j] = 0.0;

    for (int k0 = 0; k0 < D_MODEL; k0 += 16) {
        // stage H tile 128x16 (f32 -> f64, transposed)
        #pragma unroll
        for (int r = 0; r < 2; ++r) {
            const int idx = tid + r * 256;
            const int tr = idx >> 2, k4 = (idx & 3) * 4;
            const float4 v = *(const float4*)(H + (size_t)(t0 + tr) * D_MODEL + k0 + k4);
            Hs[k4 + 0][tr] = v.x; Hs[k4 + 1][tr] = v.y;
            Hs[k4 + 2][tr] = v.z; Hs[k4 + 3][tr] = v.w;
        }
        // stage M tile 64x16 (f64, transposed)
        {
            const int er = tid >> 2, k4 = (tid & 3) * 4;
            const double* mp = M + (size_t)(e0 + er) * D_MODEL + k0 + k4;
            Ms[k4 + 0][er] = mp[0]; Ms[k4 + 1][er] = mp[1];
            Ms[k4 + 2][er] = mp[2]; Ms[k4 + 3][er] = mp[3];
        }
        __syncthreads();
        #pragma unroll
        for (int kk = 0; kk < 16; ++kk) {
            double a[8], b[4];
            #pragma unroll
            for (int i = 0; i < 8; ++i) a[i] = Hs[kk][tt + 16 * i];
            #pragma unroll
            for (int j = 0; j < 4; ++j) b[j] = Ms[kk][te * 4 + j];
            #pragma unroll
            for (int i = 0; i < 8; ++i)
                #pragma unroll
                for (int j = 0; j < 4; ++j)
                    acc[i][j] += a[i] * b[j];
        }
        __syncthreads();
    }

    // epilogue: f32 affinity + f32 residual
    #pragma unroll
    for (int i = 0; i < 8; ++i) {
        const int t = t0 + tt + 16 * i;
        float4 va, vr;
        float a0 = (float)acc[i][0]; va.x = a0; vr.x = (float)(acc[i][0] - (double)a0);
        float a1 = (float)acc[i][1]; va.y = a1; vr.y = (float)(acc[i][1] - (double)a1);
        float a2 = (float)acc[i][2]; va.z = a2; vr.z = (float)(acc[i][2] - (double)a2);
        float a3 = (float)acc[i][3]; va.w = a3; vr.w = (float)(acc[i][3] - (double)a3);
        *(float4*)(aff + (size_t)t * NUM_EXPERTS + e0 + te * 4) = va;
        *(float4*)(res + (size_t)t * NUM_EXPERTS + e0 + te * 4) = vr;
    }

    // column sums of sigmoid (f64)
    #pragma unroll
    for (int j = 0; j < 4; ++j) {
        double ps = 0.0;
        #pragma unroll
        for (int i = 0; i < 8; ++i) ps += 1.0 / (1.0 + exp(-acc[i][j]));
        #pragma unroll
        for (int m = 1; m < 16; m <<= 1) ps += __shfl_xor(ps, m, 64);
        if (tt == 0) atomicAdd(&sumP[e0 + te * 4 + j], ps);
    }
}

// ---------------------------------------------------------------------------
// Kernel C: per-token top-8 on f64-reconstructed scores. One wave per token.
// ---------------------------------------------------------------------------
__global__ __launch_bounds__(256) void topk_f64(
    const float* __restrict__ aff, const float* __restrict__ res,
    const float* __restrict__ bias,
    float* __restrict__ out_idx, float* __restrict__ out_w,
    float* __restrict__ counts)
{
    const int lane = threadIdx.x & 63;
    const int wv = threadIdx.x >> 6;
    const int t = blockIdx.x * 4 + wv;

    const float4 av = *(const float4*)(aff + (size_t)t * NUM_EXPERTS + lane * 4);
    const float4 rv = *(const float4*)(res + (size_t)t * NUM_EXPERTS + lane * 4);
    const float4 bv = *(const float4*)(bias + lane * 4);

    double g[4], s[4];
    {
        double x0 = (double)av.x + (double)rv.x;
        double x1 = (double)av.y + (double)rv.y;
        double x2 = (double)av.z + (double)rv.z;
        double x3 = (double)av.w + (double)rv.w;
        g[0] = 1.0 / (1.0 + exp(-x0)); s[0] = g[0] + (double)bv.x;
        g[1] = 1.0 / (1.0 + exp(-x1)); s[1] = g[1] + (double)bv.y;
        g[2] = 1.0 / (1.0 + exp(-x2)); s[2] = g[2] + (double)bv.z;
        g[3] = 1.0 / (1.0 + exp(-x3)); s[3] = g[3] + (double)bv.w;
    }

    double wsum = 0.0, my_g = 0.0;
    int my_i = 0;

    for (int it = 0; it < TOP_K; ++it) {
        double bs = s[0], bg = g[0]; int bi = lane * 4;
        #pragma unroll
        for (int j = 1; j < 4; ++j) {
            if (s[j] > bs) { bs = s[j]; bg = g[j]; bi = lane * 4 + j; }
        }
        #pragma unroll
        for (int off = 1; off < 64; off <<= 1) {
            const double os = __shfl_xor(bs, off, 64);
            const double og = __shfl_xor(bg, off, 64);
            const int    oi = __shfl_xor(bi, off, 64);
            if (os > bs || (os == bs && oi < bi)) { bs = os; bg = og; bi = oi; }
        }
        wsum += bg;
        if (lane == it) { my_i = bi; my_g = bg; }
        if ((bi >> 2) == lane) s[bi & 3] = -1e300;
    }

    const double inv = 1.0 / (wsum + 1e-10);
    if (lane < TOP_K) {
        out_idx[(size_t)t * TOP_K + lane] = (float)my_i;
        out_w[(size_t)t * TOP_K + lane] = (float)(my_g * inv);
        atomicAdd(&counts[my_i], 1.0f);
    }
}

// ---------------------------------------------------------------------------
// Kernel D: balance loss (f64)
// ---------------------------------------------------------------------------
__global__ __launch_bounds__(256) void loss_f64(
    const double* __restrict__ sumP, const float* __restrict__ counts,
    float* __restrict__ out_loss)
{
    __shared__ double red[256];
    const int e = threadIdx.x;
    red[e] = (double)counts[e] * sumP[e];
    __syncthreads();
    #pragma unroll
    for (int sft = 128; sft > 0; sft >>= 1) {
        if (e < sft) red[e] += red[e + sft];
        __syncthreads();
    }
    if (e == 0) {
        const double denom = (double)T_TOKENS * (double)TOP_K * (double)T_TOKENS;
        out_loss[0] = (float)(0.001 * ((double)NUM_EXPERTS / (double)TOP_K) * red[0] / denom);
    }
}

extern "C" void kernel_launch(void* const* d_in, const int* in_sizes, int n_in,
                              void* d_out, int out_size, void* d_ws, size_t ws_size,
                              hipStream_t stream) {
    (void)in_sizes; (void)n_in; (void)out_size; (void)ws_size;
    const float* hidden = (const float*)d_in[0];
    const float* W      = (const float*)d_in[1];
    const float* C      = (const float*)d_in[2];
    const float* bias   = (const float*)d_in[3];
    float* out = (float*)d_out;
    char* ws   = (char*)d_ws;

    double* M      = (double*)(ws + WS_M_B);
    float*  res    = (float*)(ws + WS_RES_B);
    double* sumP   = (double*)(ws + WS_SUMP_B);
    float*  counts = (float*)(ws + WS_CNT_B);

    hipMemsetAsync(sumP, 0, NUM_EXPERTS * 8 + NUM_EXPERTS * 4, stream);

    cw_gemm_f64<<<dim3(D_MODEL / 64, NUM_EXPERTS / 32), 256, 0, stream>>>(C, W, M);

    affinity_f64<<<dim3(NUM_EXPERTS / 64, T_TOKENS / 128), 256, 0, stream>>>(
        hidden, M, out + OUT_AFF, res, sumP);

    topk_f64<<<dim3(T_TOKENS / 4), 256, 0, stream>>>(
        out + OUT_AFF, res, bias, out + OUT_IDX, out + OUT_W, counts);

    loss_f64<<<dim3(1), 256, 0, stream>>>(sumP, counts, out + OUT_LOSS);
}